// Round 2
// baseline (20774.716 us; speedup 1.0000x reference)
//
#include <hip/hip_runtime.h>

// RNN_90829968376262 — Round 4 (hardened round-3).
// Persistent cooperative scan (1 kernel for 255 steps) with:
//  - W_hh slice resident in LDS per block for all steps
//  - 8x8 register micro-tile, float4-along-K reads (LDS-balanced, ~94% FMA density)
//  - monotone-generation device barriers (releaser stores gen = t; no stale-read race)
//  - bounded spin (~7 ms bail) so a broken barrier degrades to wrong-data, never a hang
// Phase 1 (fp32 GEMM) / phase 3 (bf16 MFMA) unchanged from the verified round-2 kernel.
// Memory plan: buf = d_ws (256 MB): xh[t] overwritten in place by h_t (fp32).
//   P (4 MB K-split partials) = start of d_out; bar flags at d_out+5MB;
//   WdT (bf16 W_dense^T) = tail of d_out (final-state region, overwritten last).

#define T_STEPS 256
#define B_SZ    256
#define V_SZ    512
#define H_SZ    1024
#define BH      (B_SZ * H_SZ)          // 262144
#define M1      (T_STEPS * B_SZ)       // 65536

// persistent scan geometry
#define SC_BLOCKS  256
#define SC_THREADS 256
#define WS_STRIDE  260                 // 64 cols x 256 k (bank lc*4 -> conflict-free)
#define AS_STRIDE  40                  // 64 rows x 32 k (bank lr*8 -> 2-way, free)
#define SPIN_MAX   (1 << 17)           // ~7 ms bail; never fires when barrier is healthy

typedef __attribute__((ext_vector_type(8))) short bf16x8;
typedef __attribute__((ext_vector_type(4))) float f32x4;

__device__ inline unsigned short bf16_rne(float f) {
    unsigned u = __float_as_uint(f);
    u += 0x7fffu + ((u >> 16) & 1u);
    return (unsigned short)(u >> 16);
}

// =====================  Phase 1: fp32 GEMM 128x128 tile =====================
__global__ __launch_bounds__(256, 4)
void gemm_f32_xh(const float* __restrict__ A, const float* __restrict__ Bw,
                 const float* __restrict__ bias, float* __restrict__ C)
{
    __shared__ __align__(16) float As[16][128];   // [k][m]
    __shared__ __align__(16) float Bs[16][128];   // [k][n]
    const int tid = threadIdx.x;
    const int tx = tid & 15, ty = tid >> 4;
    const int r0 = blockIdx.y * 128, c0 = blockIdx.x * 128;
    const int ar = tid >> 1, ak = (tid & 1) * 8;
    const int bk = tid >> 4, bc = (tid & 15) * 8;

    float acc[8][8] = {};

    for (int kc = 0; kc < V_SZ; kc += 16) {
        const float* ap = A + (size_t)(r0 + ar) * V_SZ + kc + ak;
        float4 a0 = ((const float4*)ap)[0];
        float4 a1 = ((const float4*)ap)[1];
        const float* bp = Bw + (size_t)(kc + bk) * H_SZ + c0 + bc;
        float4 b0 = ((const float4*)bp)[0];
        float4 b1 = ((const float4*)bp)[1];
        __syncthreads();
        As[ak + 0][ar] = a0.x; As[ak + 1][ar] = a0.y;
        As[ak + 2][ar] = a0.z; As[ak + 3][ar] = a0.w;
        As[ak + 4][ar] = a1.x; As[ak + 5][ar] = a1.y;
        As[ak + 6][ar] = a1.z; As[ak + 7][ar] = a1.w;
        *(float4*)&Bs[bk][bc]     = b0;
        *(float4*)&Bs[bk][bc + 4] = b1;
        __syncthreads();
#pragma unroll
        for (int kk = 0; kk < 16; ++kk) {
            float ra[8], rb[8];
            *(float4*)(ra)     = *(const float4*)&As[kk][ty * 8];
            *(float4*)(ra + 4) = *(const float4*)&As[kk][ty * 8 + 4];
            *(float4*)(rb)     = *(const float4*)&Bs[kk][tx * 8];
            *(float4*)(rb + 4) = *(const float4*)&Bs[kk][tx * 8 + 4];
#pragma unroll
            for (int i = 0; i < 8; ++i)
#pragma unroll
                for (int j = 0; j < 8; ++j)
                    acc[i][j] += ra[i] * rb[j];
        }
    }

    float4 bv0 = *(const float4*)(bias + c0 + tx * 8);
    float4 bv1 = *(const float4*)(bias + c0 + tx * 8 + 4);
#pragma unroll
    for (int i = 0; i < 8; ++i) {
        float* cp = C + (size_t)(r0 + ty * 8 + i) * H_SZ + c0 + tx * 8;
        float4 o0, o1;
        o0.x = acc[i][0] + bv0.x; o0.y = acc[i][1] + bv0.y;
        o0.z = acc[i][2] + bv0.z; o0.w = acc[i][3] + bv0.w;
        o1.x = acc[i][4] + bv1.x; o1.y = acc[i][5] + bv1.y;
        o1.z = acc[i][6] + bv1.z; o1.w = acc[i][7] + bv1.w;
        ((float4*)cp)[0] = o0;
        ((float4*)cp)[1] = o1;
    }
}

// t=0: h0 = 0 -> buf[0] = tanh(buf[0])
__global__ __launch_bounds__(256)
void tanh_inplace(float* __restrict__ X)
{
    int i = (blockIdx.x * 256 + threadIdx.x) * 4;
    float4 x = *(float4*)(X + i);
    float4 o;
    o.x = tanhf(x.x); o.y = tanhf(x.y); o.z = tanhf(x.z); o.w = tanhf(x.w);
    *(float4*)(X + i) = o;
}

// =====================  Persistent scan ====================================
__global__ __launch_bounds__(256)
void init_bars(int* __restrict__ bar)
{
    bar[blockIdx.x * 256 + threadIdx.x] = 0;
}

// Monotone-generation device barrier. Slot id: cnt @ id*64, gen @ id*64+32.
// Releaser stores gen = t (step index known identically by all members);
// waiters spin on gen < t. No generation ambiguity possible. Bounded spin
// turns any residency/sync failure into wrong data instead of a hang.
__device__ __forceinline__ void bar_sync(int* __restrict__ bar, int id, int n, int t)
{
    __syncthreads();
    if (threadIdx.x == 0) {
        int* cnt = bar + id * 64;
        int* gen = bar + id * 64 + 32;
        __threadfence();   // release our h/P writes (L2 writeback, agent scope)
        int old = __hip_atomic_fetch_add(cnt, 1, __ATOMIC_ACQ_REL, __HIP_MEMORY_SCOPE_AGENT);
        if (old == n - 1) {
            __hip_atomic_store(cnt, 0, __ATOMIC_RELAXED, __HIP_MEMORY_SCOPE_AGENT);
            __hip_atomic_store(gen, t, __ATOMIC_RELEASE, __HIP_MEMORY_SCOPE_AGENT);
        } else {
            int spin = 0;
            while (__hip_atomic_load(gen, __ATOMIC_ACQUIRE, __HIP_MEMORY_SCOPE_AGENT) < t) {
                __builtin_amdgcn_s_sleep(2);
                if (++spin > SPIN_MAX) break;      // safety bail, never fires when healthy
            }
        }
        __threadfence();   // acquire side: invalidate stale L1 before re-reading peers
    }
    __syncthreads();
}

// 256 blocks x 256 threads, 1 block/CU (LDS ~149 KB).
// block bid = ks*64 + tile, tile = rowg*16 + colg.
//   rows  [rowg*64, +64)  (batch dim)
//   cols  [colg*64, +64)  (H-out dim)
//   k     [ks*256, +256)  (H-in dim, K-split)
// Per step: partial GEMM tile -> P; 4 ks-siblings sync; each finishes its 16
// rows (+xh, tanh, write h_t in place); row-group barrier (64 blocks) gates t+1.
__global__ __launch_bounds__(SC_THREADS, 1)
void scan_persistent(float* __restrict__ buf, const float* __restrict__ Whh,
                     float* __restrict__ P, int* __restrict__ bar)
{
    __shared__ __align__(16) float Ws[64 * WS_STRIDE];    // W^T slice [c][k'] 66.5 KB
    __shared__ __align__(16) float As[2 * 64 * AS_STRIDE];// h_prev chunks [r][kk] 20.5 KB
    __shared__ __align__(16) float Rb[4 * 4096];          // wave partials 64 KB

    const int tid  = threadIdx.x;
    const int bid  = blockIdx.x;
    const int ks   = bid >> 6;          // 0..3
    const int tile = bid & 63;          // 0..63
    const int rowg = tile >> 4;         // 0..3
    const int colg = tile & 15;         // 0..15
    const int b0 = rowg * 64;
    const int c0 = colg * 64;
    const int k0 = ks * 256;

    const int w  = tid >> 6;            // wave 0..3 (K-split within block)
    const int l  = tid & 63;
    const int lr = l >> 3;              // row octant
    const int lc = l & 7;               // col octant

    // ---- stage W slice transposed, once: Ws[c][k'] = Whh[k0+k'][c0+c]
    for (int idx = tid; idx < 64 * 256; idx += SC_THREADS) {
        int c = idx & 63, kp = idx >> 6;
        Ws[c * WS_STRIDE + kp] = Whh[(size_t)(k0 + kp) * H_SZ + c0 + c];
    }
    __syncthreads();

    const int sr = tid >> 3, skq = tid & 7;               // A-stage: row, k-quad
    float* Pblk = P + (size_t)(tile * 4 + ks) * 4096;
    const float* Ptile = P + (size_t)tile * 4 * 4096;

    for (int t = 1; t < T_STEPS; ++t) {
        const float* hprev = buf + (size_t)(t - 1) * BH;

        float acc[8][8];
#pragma unroll
        for (int i = 0; i < 8; ++i)
#pragma unroll
            for (int j = 0; j < 8; ++j) acc[i][j] = 0.f;

        // prologue: stage chunk 0 (rows 64 x k 32, layout As[r][kk] stride 40)
        {
            const float* ap = hprev + (size_t)(b0 + sr) * H_SZ + k0 + skq * 4;
            float4 v0 = *(const float4*)ap;
            float4 v1 = *(const float4*)(ap + (size_t)32 * H_SZ);
            *(float4*)&As[sr * AS_STRIDE + skq * 4] = v0;
            *(float4*)&As[(sr + 32) * AS_STRIDE + skq * 4] = v1;
        }
        __syncthreads();

        for (int ch = 0; ch < 8; ++ch) {
            const int cb = ch & 1, nb = cb ^ 1;
            float4 v0, v1;
            if (ch < 7) {   // issue next chunk's loads early; latency hides under FMAs
                const float* ap = hprev + (size_t)(b0 + sr) * H_SZ + k0 + (ch + 1) * 32 + skq * 4;
                v0 = *(const float4*)ap;
                v1 = *(const float4*)(ap + (size_t)32 * H_SZ);
            }
            const float* Ab = &As[cb * (64 * AS_STRIDE)];
            // wave w covers k-quads {w, w+4} of this 32-k chunk
#pragma unroll
            for (int qi = 0; qi < 2; ++qi) {
                const int kk = (w + qi * 4) * 4;          // 0..28, within chunk
                const int kp = ch * 32 + kk;              // 0..255, within k-slice
                float4 a[8], b[8];
#pragma unroll
                for (int i = 0; i < 8; ++i)
                    a[i] = *(const float4*)&Ab[(8 * i + lr) * AS_STRIDE + kk];
#pragma unroll
                for (int j = 0; j < 8; ++j)
                    b[j] = *(const float4*)&Ws[(8 * j + lc) * WS_STRIDE + kp];
#pragma unroll
                for (int i = 0; i < 8; ++i)
#pragma unroll
                    for (int j = 0; j < 8; ++j)
                        acc[i][j] += a[i].x * b[j].x + a[i].y * b[j].y
                                   + a[i].z * b[j].z + a[i].w * b[j].w;
            }
            if (ch < 7) {
                *(float4*)&As[nb * (64 * AS_STRIDE) + sr * AS_STRIDE + skq * 4] = v0;
                *(float4*)&As[nb * (64 * AS_STRIDE) + (sr + 32) * AS_STRIDE + skq * 4] = v1;
                __syncthreads();
            }
        }

        // ---- intra-block reduce: micro-order layout (i*8+j)*64 + lane (conflict-free)
#pragma unroll
        for (int i = 0; i < 8; ++i)
#pragma unroll
            for (int j = 0; j < 8; ++j)
                Rb[w * 4096 + (i * 8 + j) * 64 + l] = acc[i][j];
        __syncthreads();
#pragma unroll
        for (int u = 0; u < 4; ++u) {
            int idx = u * 1024 + tid * 4;
            float4 s0 = *(const float4*)&Rb[idx];
            float4 s1 = *(const float4*)&Rb[4096 + idx];
            float4 s2 = *(const float4*)&Rb[8192 + idx];
            float4 s3 = *(const float4*)&Rb[12288 + idx];
            float4 s;
            s.x = (s0.x + s1.x) + (s2.x + s3.x);
            s.y = (s0.y + s1.y) + (s2.y + s3.y);
            s.z = (s0.z + s1.z) + (s2.z + s3.z);
            s.w = (s0.w + s1.w) + (s2.w + s3.w);
            *(float4*)&Pblk[idx] = s;
        }

        // wait for the 4 K-split siblings of this tile
        bar_sync(bar, tile, 4, t);

        // ---- finish rows [b0+16ks, +16): sum 4 partials + xh, tanh, write h_t
        float* ht = buf + (size_t)t * BH;
#pragma unroll
        for (int m = 0; m < 4; ++m) {
            int g = w * 4 + m;                    // 0..15
            int i = 2 * ks + (g >> 3);            // absolute row octant
            int j = g & 7;
            int gi = (i * 8 + j) * 64 + l;
            float s = (Ptile[gi] + Ptile[4096 + gi])
                    + (Ptile[8192 + gi] + Ptile[12288 + gi]);
            int row = b0 + 8 * i + lr;
            int col = c0 + 8 * j + lc;
            float* hp = ht + (size_t)row * H_SZ + col;
            s += *hp;                             // xh preloaded in place
            *hp = tanhf(s);
        }

        // row-group barrier: 64 blocks (all colg, all ks) sharing these batch rows
        if (t < T_STEPS - 1) bar_sync(bar, 64 + rowg, 64, t);
    }
}

// =====================  W_dense pre-pass: transpose + cvt bf16 ==============
__global__ __launch_bounds__(256)
void cvt_wdense(const float* __restrict__ Wd, unsigned short* __restrict__ WdT)
{
    __shared__ float tile[64][65];
    const int tid = threadIdx.x;
    const int kt = blockIdx.x * 64, nt = blockIdx.y * 64;
    const int kr = tid >> 2, nc = (tid & 3) * 16;
#pragma unroll
    for (int i = 0; i < 4; ++i) {
        float4 v = *(const float4*)(Wd + (size_t)(kt + kr) * V_SZ + nt + nc + i * 4);
        tile[kr][nc + i * 4 + 0] = v.x;
        tile[kr][nc + i * 4 + 1] = v.y;
        tile[kr][nc + i * 4 + 2] = v.z;
        tile[kr][nc + i * 4 + 3] = v.w;
    }
    __syncthreads();
    const int nr = tid >> 2, kc = (tid & 3) * 16;
    unsigned words[8];
#pragma unroll
    for (int j = 0; j < 8; ++j) {
        unsigned short lo = bf16_rne(tile[kc + 2 * j][nr]);
        unsigned short hi = bf16_rne(tile[kc + 2 * j + 1][nr]);
        words[j] = (unsigned)lo | ((unsigned)hi << 16);
    }
    unsigned* wp = (unsigned*)(WdT + (size_t)(nt + nr) * H_SZ + kt + kc);
    ((uint4*)wp)[0] = make_uint4(words[0], words[1], words[2], words[3]);
    ((uint4*)wp)[1] = make_uint4(words[4], words[5], words[6], words[7]);
}

// =====================  Phase 3: bf16 MFMA GEMM 128x128 tile ================
__global__ __launch_bounds__(256, 2)
void gemm_out_mfma(const float* __restrict__ hs, const unsigned short* __restrict__ WdT,
                   const float* __restrict__ bias, float* __restrict__ out)
{
    __shared__ __align__(16) short As[128 * 40];
    __shared__ __align__(16) short Bs[128 * 32];
    const int tid = threadIdx.x;
    const int lane = tid & 63;
    const int w = tid >> 6;
    const int r0 = blockIdx.y * 128, c0 = blockIdx.x * 128;
    const int rw = (w >> 1) * 64, cw = (w & 1) * 64;

    const int s_row = tid & 127;
    const int s_kh  = tid >> 7;
    const int b_n   = tid >> 2;
    const int b_q   = tid & 3;

    f32x4 acc[4][4];
#pragma unroll
    for (int i = 0; i < 4; ++i)
#pragma unroll
        for (int j = 0; j < 4; ++j)
            acc[i][j] = (f32x4){0.f, 0.f, 0.f, 0.f};

    const int l15 = lane & 15, l16 = lane >> 4;

    for (int kc = 0; kc < H_SZ; kc += 32) {
        const float* ap = hs + (size_t)(r0 + s_row) * H_SZ + kc + s_kh * 16;
        float4 a0 = ((const float4*)ap)[0];
        float4 a1 = ((const float4*)ap)[1];
        float4 a2 = ((const float4*)ap)[2];
        float4 a3 = ((const float4*)ap)[3];
        unsigned pk[8];
        pk[0] = __builtin_amdgcn_perm(__float_as_uint(a0.y), __float_as_uint(a0.x), 0x07060302u);
        pk[1] = __builtin_amdgcn_perm(__float_as_uint(a0.w), __float_as_uint(a0.z), 0x07060302u);
        pk[2] = __builtin_amdgcn_perm(__float_as_uint(a1.y), __float_as_uint(a1.x), 0x07060302u);
        pk[3] = __builtin_amdgcn_perm(__float_as_uint(a1.w), __float_as_uint(a1.z), 0x07060302u);
        pk[4] = __builtin_amdgcn_perm(__float_as_uint(a2.y), __float_as_uint(a2.x), 0x07060302u);
        pk[5] = __builtin_amdgcn_perm(__float_as_uint(a2.w), __float_as_uint(a2.z), 0x07060302u);
        pk[6] = __builtin_amdgcn_perm(__float_as_uint(a3.y), __float_as_uint(a3.x), 0x07060302u);
        pk[7] = __builtin_amdgcn_perm(__float_as_uint(a3.w), __float_as_uint(a3.z), 0x07060302u);
        bf16x8 bld0 = *(const bf16x8*)(WdT + (size_t)(c0 + b_n) * H_SZ + kc + b_q * 8);
        bf16x8 bld1 = *(const bf16x8*)(WdT + (size_t)(c0 + b_n + 64) * H_SZ + kc + b_q * 8);
        __syncthreads();
        ((uint4*)&As[s_row * 40 + s_kh * 16])[0] = make_uint4(pk[0], pk[1], pk[2], pk[3]);
        ((uint4*)&As[s_row * 40 + s_kh * 16 + 8])[0] = make_uint4(pk[4], pk[5], pk[6], pk[7]);
        *(bf16x8*)(&Bs[b_n * 32 + b_q * 8]) = bld0;
        *(bf16x8*)(&Bs[(b_n + 64) * 32 + b_q * 8]) = bld1;
        __syncthreads();

        bf16x8 af[4], bf[4];
#pragma unroll
        for (int mi = 0; mi < 4; ++mi)
            af[mi] = *(const bf16x8*)(&As[(rw + mi * 16 + l15) * 40 + l16 * 8]);
#pragma unroll
        for (int ni = 0; ni < 4; ++ni)
            bf[ni] = *(const bf16x8*)(&Bs[(cw + ni * 16 + l15) * 32 + l16 * 8]);
#pragma unroll
        for (int mi = 0; mi < 4; ++mi)
#pragma unroll
            for (int ni = 0; ni < 4; ++ni)
                acc[mi][ni] = __builtin_amdgcn_mfma_f32_16x16x32_bf16(
                    af[mi], bf[ni], acc[mi][ni], 0, 0, 0);
    }

#pragma unroll
    for (int ni = 0; ni < 4; ++ni) {
        const int col = c0 + cw + ni * 16 + l15;
        const float bv = bias[col];
#pragma unroll
        for (int mi = 0; mi < 4; ++mi) {
            const int rowb = r0 + rw + mi * 16 + l16 * 4;
#pragma unroll
            for (int r = 0; r < 4; ++r)
                out[(size_t)(rowb + r) * V_SZ + col] = acc[mi][ni][r] + bv;
        }
    }
}

// final state copy
__global__ __launch_bounds__(256)
void copy_f4(const float* __restrict__ src, float* __restrict__ dst)
{
    int i = blockIdx.x * 256 + threadIdx.x;
    ((float4*)dst)[i] = ((const float4*)src)[i];
}

extern "C" void kernel_launch(void* const* d_in, const int* in_sizes, int n_in,
                              void* d_out, int out_size, void* d_ws, size_t ws_size,
                              hipStream_t stream)
{
    const float* inputs  = (const float*)d_in[0];
    const float* W_xh    = (const float*)d_in[1];
    const float* W_hh    = (const float*)d_in[2];
    const float* b_h     = (const float*)d_in[3];
    const float* W_dense = (const float*)d_in[4];
    const float* b_dense = (const float*)d_in[5];
    float* out = (float*)d_out;

    float* buf = (float*)d_ws;                          // 256 MB: xh -> hs in place
    float* P   = out;                                   // 4 MB K-split partials
    int*   bar = (int*)(out + 1310720);                 // barrier flags @ +5 MB
    unsigned short* WdT = (unsigned short*)(out + (size_t)M1 * V_SZ); // 1 MB tail

    // W_dense -> WdT (bf16, transposed) in the out-tail scratch region
    cvt_wdense<<<dim3(H_SZ / 64, V_SZ / 64), 256, 0, stream>>>(W_dense, WdT);

    // Phase 1: xh = inputs @ W_xh + b_h
    gemm_f32_xh<<<dim3(H_SZ / 128, M1 / 128), 256, 0, stream>>>(
        inputs, W_xh, b_h, buf);

    // t = 0
    tanh_inplace<<<dim3(BH / 1024), 256, 0, stream>>>(buf);

    // Phase 2: persistent cooperative scan (steps 1..255)
    init_bars<<<dim3(32), 256, 0, stream>>>(bar);
    {
        void* args[4];
        args[0] = (void*)&buf;
        args[1] = (void*)&W_hh;
        args[2] = (void*)&P;
        args[3] = (void*)&bar;
        hipError_t e = hipLaunchCooperativeKernel((void*)scan_persistent,
                                                  dim3(SC_BLOCKS), dim3(SC_THREADS),
                                                  args, 0, stream);
        if (e != hipSuccess) {
            // fallback: plain launch (256 blocks @ 1 block/CU co-resident in practice;
            // bounded spin guarantees forward progress even if that assumption breaks)
            scan_persistent<<<dim3(SC_BLOCKS), dim3(SC_THREADS), 0, stream>>>(
                buf, W_hh, P, bar);
        }
    }

    // Phase 3: outputs = hs @ W_dense + b_dense (bf16 MFMA)
    gemm_out_mfma<<<dim3(V_SZ / 128, M1 / 128), 256, 0, stream>>>(
        buf, WdT, b_dense, out);

    // final state (overwrites the WdT scratch tail)
    copy_f4<<<dim3(BH / 1024), 256, 0, stream>>>(
        buf + (size_t)(T_STEPS - 1) * BH, out + (size_t)M1 * V_SZ);
}

// Round 3
// 17947.765 us; speedup vs baseline: 1.1575x; 1.1575x over previous
//
#include <hip/hip_runtime.h>

// RNN_90829968376262 — Round 5.
// Round-4 post-mortem: scan_persistent 19.7ms, VALUBusy 7.3% (= modeled 5.6µs/step
// GEMM core), FETCH+WRITE 2.4GB -> 93% of time was __threadfence's buffer_wbl2/inv
// (full L2 writeback per block per step) + HBM round-trip of all shared data.
// Fix: NO fences. Cross-block data (h, P) uses relaxed AGENT-scope atomics
// (sc0 sc1 write-through/read-through, pipelined); barrier acq_rel RMW provides
// ordering. Row-group barrier is now a tree (4-wide tile x2, then 16 reps).
// Phases 1/3 unchanged. Memory plan: buf = d_ws (xh[t] -> h_t in place, fp32);
// P = start of d_out (4MB); bar @ d_out+5MB; WdT = out tail (overwritten last).

#define T_STEPS 256
#define B_SZ    256
#define V_SZ    512
#define H_SZ    1024
#define BH      (B_SZ * H_SZ)          // 262144
#define M1      (T_STEPS * B_SZ)       // 65536

#define SC_BLOCKS  256
#define SC_THREADS 256
#define WS_STRIDE  260
#define AS_STRIDE  40
#define SPIN_MAX   (1 << 17)

typedef __attribute__((ext_vector_type(8))) short bf16x8;
typedef __attribute__((ext_vector_type(4))) float f32x4;

__device__ inline unsigned short bf16_rne(float f) {
    unsigned u = __float_as_uint(f);
    u += 0x7fffu + ((u >> 16) & 1u);
    return (unsigned short)(u >> 16);
}

// ---- device-coherent (agent-scope, relaxed) data access helpers ----
// Compile to global_load/store with sc0 sc1: bypass stale L1/L2, write through to
// the coherence point. Relaxed => no serializing waitcnts; barrier RMWs order them.
__device__ __forceinline__ float2 coh_load_f2(const float* p) {
    unsigned long long u = __hip_atomic_load((unsigned long long*)p,
                                             __ATOMIC_RELAXED, __HIP_MEMORY_SCOPE_AGENT);
    float2 f;
    f.x = __uint_as_float((unsigned)u);
    f.y = __uint_as_float((unsigned)(u >> 32));
    return f;
}
__device__ __forceinline__ void coh_store_f2(float* p, float x, float y) {
    unsigned long long u = (unsigned long long)__float_as_uint(x)
                         | ((unsigned long long)__float_as_uint(y) << 32);
    __hip_atomic_store((unsigned long long*)p, u,
                       __ATOMIC_RELAXED, __HIP_MEMORY_SCOPE_AGENT);
}
__device__ __forceinline__ float coh_load_f(const float* p) {
    unsigned u = __hip_atomic_load((unsigned*)p,
                                   __ATOMIC_RELAXED, __HIP_MEMORY_SCOPE_AGENT);
    return __uint_as_float(u);
}
__device__ __forceinline__ void coh_store_f(float* p, float v) {
    __hip_atomic_store((unsigned*)p, __float_as_uint(v),
                       __ATOMIC_RELAXED, __HIP_MEMORY_SCOPE_AGENT);
}

// =====================  Phase 1: fp32 GEMM 128x128 tile =====================
__global__ __launch_bounds__(256, 4)
void gemm_f32_xh(const float* __restrict__ A, const float* __restrict__ Bw,
                 const float* __restrict__ bias, float* __restrict__ C)
{
    __shared__ __align__(16) float As[16][128];   // [k][m]
    __shared__ __align__(16) float Bs[16][128];   // [k][n]
    const int tid = threadIdx.x;
    const int tx = tid & 15, ty = tid >> 4;
    const int r0 = blockIdx.y * 128, c0 = blockIdx.x * 128;
    const int ar = tid >> 1, ak = (tid & 1) * 8;
    const int bk = tid >> 4, bc = (tid & 15) * 8;

    float acc[8][8] = {};

    for (int kc = 0; kc < V_SZ; kc += 16) {
        const float* ap = A + (size_t)(r0 + ar) * V_SZ + kc + ak;
        float4 a0 = ((const float4*)ap)[0];
        float4 a1 = ((const float4*)ap)[1];
        const float* bp = Bw + (size_t)(kc + bk) * H_SZ + c0 + bc;
        float4 b0 = ((const float4*)bp)[0];
        float4 b1 = ((const float4*)bp)[1];
        __syncthreads();
        As[ak + 0][ar] = a0.x; As[ak + 1][ar] = a0.y;
        As[ak + 2][ar] = a0.z; As[ak + 3][ar] = a0.w;
        As[ak + 4][ar] = a1.x; As[ak + 5][ar] = a1.y;
        As[ak + 6][ar] = a1.z; As[ak + 7][ar] = a1.w;
        *(float4*)&Bs[bk][bc]     = b0;
        *(float4*)&Bs[bk][bc + 4] = b1;
        __syncthreads();
#pragma unroll
        for (int kk = 0; kk < 16; ++kk) {
            float ra[8], rb[8];
            *(float4*)(ra)     = *(const float4*)&As[kk][ty * 8];
            *(float4*)(ra + 4) = *(const float4*)&As[kk][ty * 8 + 4];
            *(float4*)(rb)     = *(const float4*)&Bs[kk][tx * 8];
            *(float4*)(rb + 4) = *(const float4*)&Bs[kk][tx * 8 + 4];
#pragma unroll
            for (int i = 0; i < 8; ++i)
#pragma unroll
                for (int j = 0; j < 8; ++j)
                    acc[i][j] += ra[i] * rb[j];
        }
    }

    float4 bv0 = *(const float4*)(bias + c0 + tx * 8);
    float4 bv1 = *(const float4*)(bias + c0 + tx * 8 + 4);
#pragma unroll
    for (int i = 0; i < 8; ++i) {
        float* cp = C + (size_t)(r0 + ty * 8 + i) * H_SZ + c0 + tx * 8;
        float4 o0, o1;
        o0.x = acc[i][0] + bv0.x; o0.y = acc[i][1] + bv0.y;
        o0.z = acc[i][2] + bv0.z; o0.w = acc[i][3] + bv0.w;
        o1.x = acc[i][4] + bv1.x; o1.y = acc[i][5] + bv1.y;
        o1.z = acc[i][6] + bv1.z; o1.w = acc[i][7] + bv1.w;
        ((float4*)cp)[0] = o0;
        ((float4*)cp)[1] = o1;
    }
}

// t=0: h0 = 0 -> buf[0] = tanh(buf[0])
__global__ __launch_bounds__(256)
void tanh_inplace(float* __restrict__ X)
{
    int i = (blockIdx.x * 256 + threadIdx.x) * 4;
    float4 x = *(float4*)(X + i);
    float4 o;
    o.x = tanhf(x.x); o.y = tanhf(x.y); o.z = tanhf(x.z); o.w = tanhf(x.w);
    *(float4*)(X + i) = o;
}

// =====================  Persistent scan ====================================
__global__ __launch_bounds__(256)
void init_bars(int* __restrict__ bar)
{
    bar[blockIdx.x * 256 + threadIdx.x] = 0;
}

// Monotone-gen barrier: releaser stores gen = target (strictly increasing across
// uses of a slot); waiters spin on gen < target. acq_rel RMW = release of our
// coherent data stores (emits vmcnt(0) wait) + acquire of peers'. NO threadfence.
__device__ __forceinline__ void bar_arrive_wait(int* __restrict__ bar, int id,
                                                int n, int target)
{
    __syncthreads();
    if (threadIdx.x == 0) {
        int* cnt = bar + id * 64;
        int* gen = bar + id * 64 + 32;
        int old = __hip_atomic_fetch_add(cnt, 1, __ATOMIC_ACQ_REL, __HIP_MEMORY_SCOPE_AGENT);
        if (old == n - 1) {
            __hip_atomic_store(cnt, 0, __ATOMIC_RELAXED, __HIP_MEMORY_SCOPE_AGENT);
            __hip_atomic_store(gen, target, __ATOMIC_RELEASE, __HIP_MEMORY_SCOPE_AGENT);
        } else {
            int spin = 0;
            while (__hip_atomic_load(gen, __ATOMIC_ACQUIRE, __HIP_MEMORY_SCOPE_AGENT) < target) {
                __builtin_amdgcn_s_sleep(1);
                if (++spin > SPIN_MAX) break;   // safety: wrong-data, never a hang
            }
        }
    }
    __syncthreads();
}

// 256 blocks x 256 threads, 1 block/CU. bid = ks*64 + tile, tile = rowg*16+colg.
// rows [rowg*64,+64) x cols [colg*64,+64) x k [ks*256,+256).
// Per step: GEMM partial -> P (coherent stores); tile barrier (4, gen 2t);
// finish 16 rows (+xh, tanh, coherent h_t store); tile barrier (4, gen 2t+1);
// ks==0 rep arrives at row-group slot (16 reps); all blocks wait gen >= t.
__global__ __launch_bounds__(SC_THREADS, 1)
void scan_persistent(float* __restrict__ buf, const float* __restrict__ Whh,
                     float* __restrict__ P, int* __restrict__ bar)
{
    __shared__ __align__(16) float Ws[64 * WS_STRIDE];    // W^T slice [c][k'] 66.5 KB
    __shared__ __align__(16) float As[2 * 64 * AS_STRIDE];// h_prev chunks [r][kk] 20.5 KB
    __shared__ __align__(16) float Rb[4 * 4096];          // wave partials 64 KB

    const int tid  = threadIdx.x;
    const int bid  = blockIdx.x;
    const int ks   = bid >> 6;          // 0..3
    const int tile = bid & 63;          // 0..63
    const int rowg = tile >> 4;         // 0..3
    const int colg = tile & 15;         // 0..15
    const int b0 = rowg * 64;
    const int c0 = colg * 64;
    const int k0 = ks * 256;

    const int w  = tid >> 6;            // wave 0..3 (K-split within block)
    const int l  = tid & 63;
    const int lr = l >> 3;              // row octant
    const int lc = l & 7;               // col octant

    // W slice (read-only input, visible at kernel start): plain loads into LDS once.
    for (int idx = tid; idx < 64 * 256; idx += SC_THREADS) {
        int c = idx & 63, kp = idx >> 6;
        Ws[c * WS_STRIDE + kp] = Whh[(size_t)(k0 + kp) * H_SZ + c0 + c];
    }
    __syncthreads();

    const int sr = tid >> 3, skq = tid & 7;               // A-stage: row, k-quad
    float* Pblk = P + (size_t)(tile * 4 + ks) * 4096;
    const float* Ptile = P + (size_t)tile * 4 * 4096;

    for (int t = 1; t < T_STEPS; ++t) {
        const float* hprev = buf + (size_t)(t - 1) * BH;

        float acc[8][8];
#pragma unroll
        for (int i = 0; i < 8; ++i)
#pragma unroll
            for (int j = 0; j < 8; ++j) acc[i][j] = 0.f;

        // prologue: stage chunk 0 (coherent loads: h written by peer blocks)
        {
            const float* ap  = hprev + (size_t)(b0 + sr) * H_SZ + k0 + skq * 4;
            const float* ap2 = ap + (size_t)32 * H_SZ;
            float2 p0 = coh_load_f2(ap),  p1 = coh_load_f2(ap + 2);
            float2 q0 = coh_load_f2(ap2), q1 = coh_load_f2(ap2 + 2);
            float4 v0 = make_float4(p0.x, p0.y, p1.x, p1.y);
            float4 v1 = make_float4(q0.x, q0.y, q1.x, q1.y);
            *(float4*)&As[sr * AS_STRIDE + skq * 4] = v0;
            *(float4*)&As[(sr + 32) * AS_STRIDE + skq * 4] = v1;
        }
        __syncthreads();

        for (int ch = 0; ch < 8; ++ch) {
            const int cb = ch & 1, nb = cb ^ 1;
            float4 v0, v1;
            if (ch < 7) {   // issue next chunk's coherent loads; hide under FMAs
                const float* ap  = hprev + (size_t)(b0 + sr) * H_SZ + k0 + (ch + 1) * 32 + skq * 4;
                const float* ap2 = ap + (size_t)32 * H_SZ;
                float2 p0 = coh_load_f2(ap),  p1 = coh_load_f2(ap + 2);
                float2 q0 = coh_load_f2(ap2), q1 = coh_load_f2(ap2 + 2);
                v0 = make_float4(p0.x, p0.y, p1.x, p1.y);
                v1 = make_float4(q0.x, q0.y, q1.x, q1.y);
            }
            const float* Ab = &As[cb * (64 * AS_STRIDE)];
#pragma unroll
            for (int qi = 0; qi < 2; ++qi) {
                const int kk = (w + qi * 4) * 4;          // within chunk
                const int kp = ch * 32 + kk;              // within k-slice
                float4 a[8], b[8];
#pragma unroll
                for (int i = 0; i < 8; ++i)
                    a[i] = *(const float4*)&Ab[(8 * i + lr) * AS_STRIDE + kk];
#pragma unroll
                for (int j = 0; j < 8; ++j)
                    b[j] = *(const float4*)&Ws[(8 * j + lc) * WS_STRIDE + kp];
#pragma unroll
                for (int i = 0; i < 8; ++i)
#pragma unroll
                    for (int j = 0; j < 8; ++j)
                        acc[i][j] += a[i].x * b[j].x + a[i].y * b[j].y
                                   + a[i].z * b[j].z + a[i].w * b[j].w;
            }
            if (ch < 7) {
                *(float4*)&As[nb * (64 * AS_STRIDE) + sr * AS_STRIDE + skq * 4] = v0;
                *(float4*)&As[nb * (64 * AS_STRIDE) + (sr + 32) * AS_STRIDE + skq * 4] = v1;
                __syncthreads();
            }
        }

        // ---- intra-block reduce (LDS), then coherent P stores
#pragma unroll
        for (int i = 0; i < 8; ++i)
#pragma unroll
            for (int j = 0; j < 8; ++j)
                Rb[w * 4096 + (i * 8 + j) * 64 + l] = acc[i][j];
        __syncthreads();
#pragma unroll
        for (int u = 0; u < 4; ++u) {
            int idx = u * 1024 + tid * 4;
            float4 s0 = *(const float4*)&Rb[idx];
            float4 s1 = *(const float4*)&Rb[4096 + idx];
            float4 s2 = *(const float4*)&Rb[8192 + idx];
            float4 s3 = *(const float4*)&Rb[12288 + idx];
            float sx = (s0.x + s1.x) + (s2.x + s3.x);
            float sy = (s0.y + s1.y) + (s2.y + s3.y);
            float sz = (s0.z + s1.z) + (s2.z + s3.z);
            float sw = (s0.w + s1.w) + (s2.w + s3.w);
            coh_store_f2(Pblk + idx,     sx, sy);
            coh_store_f2(Pblk + idx + 2, sz, sw);
        }

        // P ready among the 4 K-split siblings
        bar_arrive_wait(bar, tile, 4, 2 * t);

        // ---- finish rows [b0+16ks, +16): sum partials + xh, tanh, coherent store
        float* ht = buf + (size_t)t * BH;
#pragma unroll
        for (int m = 0; m < 4; ++m) {
            int g = w * 4 + m;                    // 0..15
            int i = 2 * ks + (g >> 3);            // absolute row octant
            int j = g & 7;
            int gi = (i * 8 + j) * 64 + l;
            float s = (coh_load_f(Ptile + gi) + coh_load_f(Ptile + 4096 + gi))
                    + (coh_load_f(Ptile + 8192 + gi) + coh_load_f(Ptile + 12288 + gi));
            int row = b0 + 8 * i + lr;
            int col = c0 + 8 * j + lc;
            float* hp = ht + (size_t)row * H_SZ + col;
            s += coh_load_f(hp);                  // xh preloaded in place (phase 1)
            coh_store_f(hp, tanhf(s));
        }

        if (t < T_STEPS - 1) {
            // all h-writes of this tile's 64 rows done
            bar_arrive_wait(bar, tile, 4, 2 * t + 1);
            // tree: one rep per tile arrives at the row-group slot (16 reps)
            if (threadIdx.x == 0) {
                int* cnt = bar + (64 + rowg) * 64;
                int* gen = bar + (64 + rowg) * 64 + 32;
                if (ks == 0) {
                    int old = __hip_atomic_fetch_add(cnt, 1, __ATOMIC_ACQ_REL,
                                                     __HIP_MEMORY_SCOPE_AGENT);
                    if (old == 15) {
                        __hip_atomic_store(cnt, 0, __ATOMIC_RELAXED, __HIP_MEMORY_SCOPE_AGENT);
                        __hip_atomic_store(gen, t, __ATOMIC_RELEASE, __HIP_MEMORY_SCOPE_AGENT);
                    }
                }
                int spin = 0;
                while (__hip_atomic_load(gen, __ATOMIC_ACQUIRE, __HIP_MEMORY_SCOPE_AGENT) < t) {
                    __builtin_amdgcn_s_sleep(1);
                    if (++spin > SPIN_MAX) break;
                }
            }
            __syncthreads();
        }
    }
}

// =====================  W_dense pre-pass: transpose + cvt bf16 ==============
__global__ __launch_bounds__(256)
void cvt_wdense(const float* __restrict__ Wd, unsigned short* __restrict__ WdT)
{
    __shared__ float tile[64][65];
    const int tid = threadIdx.x;
    const int kt = blockIdx.x * 64, nt = blockIdx.y * 64;
    const int kr = tid >> 2, nc = (tid & 3) * 16;
#pragma unroll
    for (int i = 0; i < 4; ++i) {
        float4 v = *(const float4*)(Wd + (size_t)(kt + kr) * V_SZ + nt + nc + i * 4);
        tile[kr][nc + i * 4 + 0] = v.x;
        tile[kr][nc + i * 4 + 1] = v.y;
        tile[kr][nc + i * 4 + 2] = v.z;
        tile[kr][nc + i * 4 + 3] = v.w;
    }
    __syncthreads();
    const int nr = tid >> 2, kc = (tid & 3) * 16;
    unsigned words[8];
#pragma unroll
    for (int j = 0; j < 8; ++j) {
        unsigned short lo = bf16_rne(tile[kc + 2 * j][nr]);
        unsigned short hi = bf16_rne(tile[kc + 2 * j + 1][nr]);
        words[j] = (unsigned)lo | ((unsigned)hi << 16);
    }
    unsigned* wp = (unsigned*)(WdT + (size_t)(nt + nr) * H_SZ + kt + kc);
    ((uint4*)wp)[0] = make_uint4(words[0], words[1], words[2], words[3]);
    ((uint4*)wp)[1] = make_uint4(words[4], words[5], words[6], words[7]);
}

// =====================  Phase 3: bf16 MFMA GEMM 128x128 tile ================
__global__ __launch_bounds__(256, 2)
void gemm_out_mfma(const float* __restrict__ hs, const unsigned short* __restrict__ WdT,
                   const float* __restrict__ bias, float* __restrict__ out)
{
    __shared__ __align__(16) short As[128 * 40];
    __shared__ __align__(16) short Bs[128 * 32];
    const int tid = threadIdx.x;
    const int lane = tid & 63;
    const int w = tid >> 6;
    const int r0 = blockIdx.y * 128, c0 = blockIdx.x * 128;
    const int rw = (w >> 1) * 64, cw = (w & 1) * 64;

    const int s_row = tid & 127;
    const int s_kh  = tid >> 7;
    const int b_n   = tid >> 2;
    const int b_q   = tid & 3;

    f32x4 acc[4][4];
#pragma unroll
    for (int i = 0; i < 4; ++i)
#pragma unroll
        for (int j = 0; j < 4; ++j)
            acc[i][j] = (f32x4){0.f, 0.f, 0.f, 0.f};

    const int l15 = lane & 15, l16 = lane >> 4;

    for (int kc = 0; kc < H_SZ; kc += 32) {
        const float* ap = hs + (size_t)(r0 + s_row) * H_SZ + kc + s_kh * 16;
        float4 a0 = ((const float4*)ap)[0];
        float4 a1 = ((const float4*)ap)[1];
        float4 a2 = ((const float4*)ap)[2];
        float4 a3 = ((const float4*)ap)[3];
        unsigned pk[8];
        pk[0] = __builtin_amdgcn_perm(__float_as_uint(a0.y), __float_as_uint(a0.x), 0x07060302u);
        pk[1] = __builtin_amdgcn_perm(__float_as_uint(a0.w), __float_as_uint(a0.z), 0x07060302u);
        pk[2] = __builtin_amdgcn_perm(__float_as_uint(a1.y), __float_as_uint(a1.x), 0x07060302u);
        pk[3] = __builtin_amdgcn_perm(__float_as_uint(a1.w), __float_as_uint(a1.z), 0x07060302u);
        pk[4] = __builtin_amdgcn_perm(__float_as_uint(a2.y), __float_as_uint(a2.x), 0x07060302u);
        pk[5] = __builtin_amdgcn_perm(__float_as_uint(a2.w), __float_as_uint(a2.z), 0x07060302u);
        pk[6] = __builtin_amdgcn_perm(__float_as_uint(a3.y), __float_as_uint(a3.x), 0x07060302u);
        pk[7] = __builtin_amdgcn_perm(__float_as_uint(a3.w), __float_as_uint(a3.z), 0x07060302u);
        bf16x8 bld0 = *(const bf16x8*)(WdT + (size_t)(c0 + b_n) * H_SZ + kc + b_q * 8);
        bf16x8 bld1 = *(const bf16x8*)(WdT + (size_t)(c0 + b_n + 64) * H_SZ + kc + b_q * 8);
        __syncthreads();
        ((uint4*)&As[s_row * 40 + s_kh * 16])[0] = make_uint4(pk[0], pk[1], pk[2], pk[3]);
        ((uint4*)&As[s_row * 40 + s_kh * 16 + 8])[0] = make_uint4(pk[4], pk[5], pk[6], pk[7]);
        *(bf16x8*)(&Bs[b_n * 32 + b_q * 8]) = bld0;
        *(bf16x8*)(&Bs[(b_n + 64) * 32 + b_q * 8]) = bld1;
        __syncthreads();

        bf16x8 af[4], bf[4];
#pragma unroll
        for (int mi = 0; mi < 4; ++mi)
            af[mi] = *(const bf16x8*)(&As[(rw + mi * 16 + l15) * 40 + l16 * 8]);
#pragma unroll
        for (int ni = 0; ni < 4; ++ni)
            bf[ni] = *(const bf16x8*)(&Bs[(cw + ni * 16 + l15) * 32 + l16 * 8]);
#pragma unroll
        for (int mi = 0; mi < 4; ++mi)
#pragma unroll
            for (int ni = 0; ni < 4; ++ni)
                acc[mi][ni] = __builtin_amdgcn_mfma_f32_16x16x32_bf16(
                    af[mi], bf[ni], acc[mi][ni], 0, 0, 0);
    }

#pragma unroll
    for (int ni = 0; ni < 4; ++ni) {
        const int col = c0 + cw + ni * 16 + l15;
        const float bv = bias[col];
#pragma unroll
        for (int mi = 0; mi < 4; ++mi) {
            const int rowb = r0 + rw + mi * 16 + l16 * 4;
#pragma unroll
            for (int r = 0; r < 4; ++r)
                out[(size_t)(rowb + r) * V_SZ + col] = acc[mi][ni][r] + bv;
        }
    }
}

// final state copy
__global__ __launch_bounds__(256)
void copy_f4(const float* __restrict__ src, float* __restrict__ dst)
{
    int i = blockIdx.x * 256 + threadIdx.x;
    ((float4*)dst)[i] = ((const float4*)src)[i];
}

extern "C" void kernel_launch(void* const* d_in, const int* in_sizes, int n_in,
                              void* d_out, int out_size, void* d_ws, size_t ws_size,
                              hipStream_t stream)
{
    const float* inputs  = (const float*)d_in[0];
    const float* W_xh    = (const float*)d_in[1];
    const float* W_hh    = (const float*)d_in[2];
    const float* b_h     = (const float*)d_in[3];
    const float* W_dense = (const float*)d_in[4];
    const float* b_dense = (const float*)d_in[5];
    float* out = (float*)d_out;

    float* buf = (float*)d_ws;                          // xh -> hs in place
    float* P   = out;                                   // 4 MB K-split partials
    int*   bar = (int*)(out + 1310720);                 // barrier flags @ +5 MB
    unsigned short* WdT = (unsigned short*)(out + (size_t)M1 * V_SZ); // 1 MB tail

    cvt_wdense<<<dim3(H_SZ / 64, V_SZ / 64), 256, 0, stream>>>(W_dense, WdT);

    gemm_f32_xh<<<dim3(H_SZ / 128, M1 / 128), 256, 0, stream>>>(
        inputs, W_xh, b_h, buf);

    tanh_inplace<<<dim3(BH / 1024), 256, 0, stream>>>(buf);

    init_bars<<<dim3(32), 256, 0, stream>>>(bar);
    {
        void* args[4];
        args[0] = (void*)&buf;
        args[1] = (void*)&W_hh;
        args[2] = (void*)&P;
        args[3] = (void*)&bar;
        hipError_t e = hipLaunchCooperativeKernel((void*)scan_persistent,
                                                  dim3(SC_BLOCKS), dim3(SC_THREADS),
                                                  args, 0, stream);
        if (e != hipSuccess) {
            scan_persistent<<<dim3(SC_BLOCKS), dim3(SC_THREADS), 0, stream>>>(
                buf, W_hh, P, bar);
        }
    }

    gemm_out_mfma<<<dim3(V_SZ / 128, M1 / 128), 256, 0, stream>>>(
        buf, WdT, b_dense, out);

    copy_f4<<<dim3(BH / 1024), 256, 0, stream>>>(
        buf + (size_t)(T_STEPS - 1) * BH, out + (size_t)M1 * V_SZ);
}

// Round 6
// 5580.601 us; speedup vs baseline: 3.7227x; 3.2161x over previous
//
#include <hip/hip_runtime.h>

// RNN_90829968376262 — Round 9 (= round 7 with the inline-asm operand fix).
// r8 failed to COMPILE: struct float4 can't be a "v" asm operand; use
// ext_vector_type(4) float (f32x4) register tuples instead (bf16x8 pattern).
// Design (unchanged): persistent scan, fence-free exchange:
//  - h/P/xh via inline-asm global_*_dwordx4 sc1 (pipelined, MALL-coherent,
//    no XCD assumptions, no cache invalidates)
//  - barriers: RELAXED atomics only; ordering via explicit s_waitcnt vmcnt(0);
//    no-reset counters (leader cond old == n*t-1) -> no reset race
//  - bounded spin -> wrong-data on failure, never a hang
// Phases 1/3 unchanged (verified r2). Memory: buf = d_ws (xh->h in place);
// P = out[0..4MB); FL flags @ out+5.2MB; WdT = out tail (overwritten last).

#define T_STEPS 256
#define B_SZ    256
#define V_SZ    512
#define H_SZ    1024
#define BH      (B_SZ * H_SZ)          // 262144
#define M1      (T_STEPS * B_SZ)       // 65536

#define SC_THREADS 256
#define WS_STRIDE  260
#define AS_STRIDE  40
#define SPIN_MAX   (1 << 14)           // bail cap; real waits are <50 us

typedef __attribute__((ext_vector_type(8))) short bf16x8;
typedef __attribute__((ext_vector_type(4))) float f32x4;

__device__ inline unsigned short bf16_rne(float f) {
    unsigned u = __float_as_uint(f);
    u += 0x7fffu + ((u >> 16) & 1u);
    return (unsigned short)(u >> 16);
}

// ---- MALL-coherent (sc1) plain vector ops: pipelined, bypass stale L1/L2 ----
// ext_vector_type operands => native VGPR tuples (struct float4 is rejected).
__device__ __forceinline__ f32x4 ld_sc1_v4(const float* p) {
    f32x4 r;
    asm volatile("global_load_dwordx4 %0, %1, off sc1" : "=v"(r) : "v"(p));
    return r;
}
__device__ __forceinline__ void st_sc1_v4(float* p, f32x4 v) {
    asm volatile("global_store_dwordx4 %0, %1, off sc1" :: "v"(p), "v"(v) : "memory");
}
__device__ __forceinline__ float ld_sc1_f(const float* p) {
    float r;
    asm volatile("global_load_dword %0, %1, off sc1" : "=v"(r) : "v"(p));
    return r;
}
__device__ __forceinline__ void st_sc1_f(float* p, float v) {
    asm volatile("global_store_dword %0, %1, off sc1" :: "v"(p), "v"(v) : "memory");
}
// wait for my sc1 ops; sched_barrier stops hipcc hoisting uses above it (rule #18)
__device__ __forceinline__ void vm_drain() {
    asm volatile("s_waitcnt vmcnt(0)" ::: "memory");
    __builtin_amdgcn_sched_barrier(0);
}

// =====================  Phase 1: fp32 GEMM 128x128 tile =====================
__global__ __launch_bounds__(256, 4)
void gemm_f32_xh(const float* __restrict__ A, const float* __restrict__ Bw,
                 const float* __restrict__ bias, float* __restrict__ C)
{
    __shared__ __align__(16) float As[16][128];   // [k][m]
    __shared__ __align__(16) float Bs[16][128];   // [k][n]
    const int tid = threadIdx.x;
    const int tx = tid & 15, ty = tid >> 4;
    const int r0 = blockIdx.y * 128, c0 = blockIdx.x * 128;
    const int ar = tid >> 1, ak = (tid & 1) * 8;
    const int bk = tid >> 4, bc = (tid & 15) * 8;

    float acc[8][8] = {};

    for (int kc = 0; kc < V_SZ; kc += 16) {
        const float* ap = A + (size_t)(r0 + ar) * V_SZ + kc + ak;
        float4 a0 = ((const float4*)ap)[0];
        float4 a1 = ((const float4*)ap)[1];
        const float* bp = Bw + (size_t)(kc + bk) * H_SZ + c0 + bc;
        float4 b0 = ((const float4*)bp)[0];
        float4 b1 = ((const float4*)bp)[1];
        __syncthreads();
        As[ak + 0][ar] = a0.x; As[ak + 1][ar] = a0.y;
        As[ak + 2][ar] = a0.z; As[ak + 3][ar] = a0.w;
        As[ak + 4][ar] = a1.x; As[ak + 5][ar] = a1.y;
        As[ak + 6][ar] = a1.z; As[ak + 7][ar] = a1.w;
        *(float4*)&Bs[bk][bc]     = b0;
        *(float4*)&Bs[bk][bc + 4] = b1;
        __syncthreads();
#pragma unroll
        for (int kk = 0; kk < 16; ++kk) {
            float ra[8], rb[8];
            *(float4*)(ra)     = *(const float4*)&As[kk][ty * 8];
            *(float4*)(ra + 4) = *(const float4*)&As[kk][ty * 8 + 4];
            *(float4*)(rb)     = *(const float4*)&Bs[kk][tx * 8];
            *(float4*)(rb + 4) = *(const float4*)&Bs[kk][tx * 8 + 4];
#pragma unroll
            for (int i = 0; i < 8; ++i)
#pragma unroll
                for (int j = 0; j < 8; ++j)
                    acc[i][j] += ra[i] * rb[j];
        }
    }

    float4 bv0 = *(const float4*)(bias + c0 + tx * 8);
    float4 bv1 = *(const float4*)(bias + c0 + tx * 8 + 4);
#pragma unroll
    for (int i = 0; i < 8; ++i) {
        float* cp = C + (size_t)(r0 + ty * 8 + i) * H_SZ + c0 + tx * 8;
        float4 o0, o1;
        o0.x = acc[i][0] + bv0.x; o0.y = acc[i][1] + bv0.y;
        o0.z = acc[i][2] + bv0.z; o0.w = acc[i][3] + bv0.w;
        o1.x = acc[i][4] + bv1.x; o1.y = acc[i][5] + bv1.y;
        o1.z = acc[i][6] + bv1.z; o1.w = acc[i][7] + bv1.w;
        ((float4*)cp)[0] = o0;
        ((float4*)cp)[1] = o1;
    }
}

// t=0: h0 = 0 -> buf[0] = tanh(buf[0])
__global__ __launch_bounds__(256)
void tanh_inplace(float* __restrict__ X)
{
    int i = (blockIdx.x * 256 + threadIdx.x) * 4;
    float4 x = *(float4*)(X + i);
    float4 o;
    o.x = tanhf(x.x); o.y = tanhf(x.y); o.z = tanhf(x.z); o.w = tanhf(x.w);
    *(float4*)(X + i) = o;
}

// =====================  Persistent scan ====================================
__global__ __launch_bounds__(256)
void init_bars(int* __restrict__ bar)
{
    bar[blockIdx.x * 256 + threadIdx.x] = 0;
}

// Relaxed-only device barrier. Slot id: cnt @ id*32, gen @ id*32+16 (64B apart).
// cnt is NEVER reset: after the t-th use of a slot with n members, cnt == n*t,
// so the releaser is whoever sees old == n*t-1. No acquire/release anywhere:
// data ordering comes from vm_drain() (sc1 data already at MALL) + the atomics
// executing at MALL. Bounded spin -> fail-fast (absmax), never a hang.
__device__ __forceinline__ void bar_arrive_wait(int* __restrict__ FLc, int id,
                                                int n, int t)
{
    asm volatile("s_waitcnt vmcnt(0)" ::: "memory");   // every wave drains sc1 ops
    __syncthreads();
    if (threadIdx.x == 0) {
        int* cnt = FLc + id * 32;
        int* gen = FLc + id * 32 + 16;
        int old = __hip_atomic_fetch_add(cnt, 1, __ATOMIC_RELAXED, __HIP_MEMORY_SCOPE_AGENT);
        if (old == n * t - 1) {
            __hip_atomic_store(gen, t, __ATOMIC_RELAXED, __HIP_MEMORY_SCOPE_AGENT);
        } else {
            int spin = 0;
            while (__hip_atomic_load(gen, __ATOMIC_RELAXED, __HIP_MEMORY_SCOPE_AGENT) < t) {
                __builtin_amdgcn_s_sleep(1);
                if (++spin > SPIN_MAX) break;
            }
        }
    }
    __syncthreads();
}

// 256 blocks x 256 threads, 1 block/CU (LDS 151 KB). bid = ks*64 + tile,
// tile = rowg*16 + colg. rows [rowg*64,+64) x cols [colg*64,+64) x k [ks*256,+256).
// Per step: GEMM partial -> Rb reduce -> P (sc1); barA(tile,4); finish 16 rows
// (+xh, tanh, h sc1); barB tile(4) then rowg tree (16 reps); next t.
__global__ __launch_bounds__(SC_THREADS, 1)
void scan_persistent(float* __restrict__ buf, const float* __restrict__ Whh,
                     float* __restrict__ P, int* __restrict__ FL)
{
    __shared__ __align__(16) float Ws[64 * WS_STRIDE];    // W^T slice [c][k'] 66.5 KB
    __shared__ __align__(16) float As[2 * 64 * AS_STRIDE];// h_prev chunks [r][kk] 20.5 KB
    __shared__ __align__(16) float Rb[4 * 4096];          // wave partials 64 KB

    const int tid  = threadIdx.x;
    const int bid  = blockIdx.x;
    const int ks   = bid >> 6;          // 0..3
    const int tile = bid & 63;          // 0..63
    const int rowg = tile >> 4;         // 0..3
    const int colg = tile & 15;         // 0..15
    const int b0 = rowg * 64;
    const int c0 = colg * 64;
    const int k0 = ks * 256;

    const int w  = tid >> 6;            // wave 0..3 (K-split within block)
    const int l  = tid & 63;
    const int lr = l >> 3;              // row octant
    const int lc = l & 7;               // col octant

    // W slice (read-only input, visible at kernel start): plain loads, once.
    for (int idx = tid; idx < 64 * 256; idx += SC_THREADS) {
        int c = idx & 63, kp = idx >> 6;
        Ws[c * WS_STRIDE + kp] = Whh[(size_t)(k0 + kp) * H_SZ + c0 + c];
    }
    __syncthreads();

    const int sr = tid >> 3, skq = tid & 7;               // A-stage: row, k-quad
    float* Pblk = P + (size_t)(tile * 4 + ks) * 4096;
    const float* Ptile = P + (size_t)tile * 4 * 4096;

    for (int t = 1; t < T_STEPS; ++t) {
        const float* hprev = buf + (size_t)(t - 1) * BH;

        float acc[8][8];
#pragma unroll
        for (int i = 0; i < 8; ++i)
#pragma unroll
            for (int j = 0; j < 8; ++j) acc[i][j] = 0.f;

        // prologue: stage chunk 0 (sc1: h written by peer blocks at MALL)
        {
            const float* ap = hprev + (size_t)(b0 + sr) * H_SZ + k0 + skq * 4;
            f32x4 v0 = ld_sc1_v4(ap);
            f32x4 v1 = ld_sc1_v4(ap + (size_t)32 * H_SZ);
            vm_drain();
            *(f32x4*)&As[sr * AS_STRIDE + skq * 4] = v0;
            *(f32x4*)&As[(sr + 32) * AS_STRIDE + skq * 4] = v1;
        }
        __syncthreads();

        for (int ch = 0; ch < 8; ++ch) {
            const int cb = ch & 1, nb = cb ^ 1;
            f32x4 v0, v1;
            if (ch < 7) {   // issue next chunk's sc1 loads; latency hides under FMAs
                const float* ap = hprev + (size_t)(b0 + sr) * H_SZ + k0 + (ch + 1) * 32 + skq * 4;
                v0 = ld_sc1_v4(ap);
                v1 = ld_sc1_v4(ap + (size_t)32 * H_SZ);
            }
            const float* Ab = &As[cb * (64 * AS_STRIDE)];
#pragma unroll
            for (int qi = 0; qi < 2; ++qi) {
                const int kk = (w + qi * 4) * 4;          // within chunk
                const int kp = ch * 32 + kk;              // within k-slice
                float4 a[8], b[8];
#pragma unroll
                for (int i = 0; i < 8; ++i)
                    a[i] = *(const float4*)&Ab[(8 * i + lr) * AS_STRIDE + kk];
#pragma unroll
                for (int j = 0; j < 8; ++j)
                    b[j] = *(const float4*)&Ws[(8 * j + lc) * WS_STRIDE + kp];
#pragma unroll
                for (int i = 0; i < 8; ++i)
#pragma unroll
                    for (int j = 0; j < 8; ++j)
                        acc[i][j] += a[i].x * b[j].x + a[i].y * b[j].y
                                   + a[i].z * b[j].z + a[i].w * b[j].w;
            }
            if (ch < 7) {
                vm_drain();                       // v0/v1 valid before LDS write
                *(f32x4*)&As[nb * (64 * AS_STRIDE) + sr * AS_STRIDE + skq * 4] = v0;
                *(f32x4*)&As[nb * (64 * AS_STRIDE) + (sr + 32) * AS_STRIDE + skq * 4] = v1;
                __syncthreads();
            }
        }

        // ---- intra-block reduce (LDS), then sc1 P stores
#pragma unroll
        for (int i = 0; i < 8; ++i)
#pragma unroll
            for (int j = 0; j < 8; ++j)
                Rb[w * 4096 + (i * 8 + j) * 64 + l] = acc[i][j];
        __syncthreads();
#pragma unroll
        for (int u = 0; u < 4; ++u) {
            int idx = u * 1024 + tid * 4;
            float4 s0 = *(const float4*)&Rb[idx];
            float4 s1 = *(const float4*)&Rb[4096 + idx];
            float4 s2 = *(const float4*)&Rb[8192 + idx];
            float4 s3 = *(const float4*)&Rb[12288 + idx];
            f32x4 s;
            s.x = (s0.x + s1.x) + (s2.x + s3.x);
            s.y = (s0.y + s1.y) + (s2.y + s3.y);
            s.z = (s0.z + s1.z) + (s2.z + s3.z);
            s.w = (s0.w + s1.w) + (s2.w + s3.w);
            st_sc1_v4(Pblk + idx, s);
        }

        // P visible at MALL among the 4 K-split siblings
        bar_arrive_wait(FL, tile, 4, t);

        // ---- finish rows [b0+16ks, +16): sum partials + xh, tanh, h sc1 store
        float* ht = buf + (size_t)t * BH;
        float pv[4][4], xv[4];
#pragma unroll
        for (int m = 0; m < 4; ++m) {
            int g = w * 4 + m;                    // 0..15
            int i = 2 * ks + (g >> 3);            // absolute row octant
            int j = g & 7;
            int gi = (i * 8 + j) * 64 + l;
            pv[m][0] = ld_sc1_f(Ptile + gi);
            pv[m][1] = ld_sc1_f(Ptile + 4096 + gi);
            pv[m][2] = ld_sc1_f(Ptile + 8192 + gi);
            pv[m][3] = ld_sc1_f(Ptile + 12288 + gi);
            xv[m] = ld_sc1_f(ht + (size_t)(b0 + 8 * i + lr) * H_SZ + c0 + 8 * j + lc);
        }
        vm_drain();
#pragma unroll
        for (int m = 0; m < 4; ++m) {
            int g = w * 4 + m;
            int i = 2 * ks + (g >> 3);
            int j = g & 7;
            float s = (pv[m][0] + pv[m][1]) + (pv[m][2] + pv[m][3]) + xv[m];
            st_sc1_f(ht + (size_t)(b0 + 8 * i + lr) * H_SZ + c0 + 8 * j + lc, tanhf(s));
        }

        if (t < T_STEPS - 1) {
            // h writes of this tile's 64 rows done (vmcnt drain inside the bar)
            bar_arrive_wait(FL, 64 + tile, 4, t);
            // tree: ks==0 rep per tile arrives at the row-group slot (16 reps)
            if (threadIdx.x == 0) {
                int* cnt = FL + (128 + rowg) * 32;
                int* gen = FL + (128 + rowg) * 32 + 16;
                if (ks == 0) {
                    int old = __hip_atomic_fetch_add(cnt, 1, __ATOMIC_RELAXED,
                                                     __HIP_MEMORY_SCOPE_AGENT);
                    if (old == 16 * t - 1)
                        __hip_atomic_store(gen, t, __ATOMIC_RELAXED,
                                           __HIP_MEMORY_SCOPE_AGENT);
                }
                int spin = 0;
                while (__hip_atomic_load(gen, __ATOMIC_RELAXED,
                                         __HIP_MEMORY_SCOPE_AGENT) < t) {
                    __builtin_amdgcn_s_sleep(1);
                    if (++spin > SPIN_MAX) break;
                }
            }
            __syncthreads();
        }
    }
}

// =====================  W_dense pre-pass: transpose + cvt bf16 ==============
__global__ __launch_bounds__(256)
void cvt_wdense(const float* __restrict__ Wd, unsigned short* __restrict__ WdT)
{
    __shared__ float tile[64][65];
    const int tid = threadIdx.x;
    const int kt = blockIdx.x * 64, nt = blockIdx.y * 64;
    const int kr = tid >> 2, nc = (tid & 3) * 16;
#pragma unroll
    for (int i = 0; i < 4; ++i) {
        float4 v = *(const float4*)(Wd + (size_t)(kt + kr) * V_SZ + nt + nc + i * 4);
        tile[kr][nc + i * 4 + 0] = v.x;
        tile[kr][nc + i * 4 + 1] = v.y;
        tile[kr][nc + i * 4 + 2] = v.z;
        tile[kr][nc + i * 4 + 3] = v.w;
    }
    __syncthreads();
    const int nr = tid >> 2, kc = (tid & 3) * 16;
    unsigned words[8];
#pragma unroll
    for (int j = 0; j < 8; ++j) {
        unsigned short lo = bf16_rne(tile[kc + 2 * j][nr]);
        unsigned short hi = bf16_rne(tile[kc + 2 * j + 1][nr]);
        words[j] = (unsigned)lo | ((unsigned)hi << 16);
    }
    unsigned* wp = (unsigned*)(WdT + (size_t)(nt + nr) * H_SZ + kt + kc);
    ((uint4*)wp)[0] = make_uint4(words[0], words[1], words[2], words[3]);
    ((uint4*)wp)[1] = make_uint4(words[4], words[5], words[6], words[7]);
}

// =====================  Phase 3: bf16 MFMA GEMM 128x128 tile ================
__global__ __launch_bounds__(256, 2)
void gemm_out_mfma(const float* __restrict__ hs, const unsigned short* __restrict__ WdT,
                   const float* __restrict__ bias, float* __restrict__ out)
{
    __shared__ __align__(16) short As[128 * 40];
    __shared__ __align__(16) short Bs[128 * 32];
    const int tid = threadIdx.x;
    const int lane = tid & 63;
    const int w = tid >> 6;
    const int r0 = blockIdx.y * 128, c0 = blockIdx.x * 128;
    const int rw = (w >> 1) * 64, cw = (w & 1) * 64;

    const int s_row = tid & 127;
    const int s_kh  = tid >> 7;
    const int b_n   = tid >> 2;
    const int b_q   = tid & 3;

    f32x4 acc[4][4];
#pragma unroll
    for (int i = 0; i < 4; ++i)
#pragma unroll
        for (int j = 0; j < 4; ++j)
            acc[i][j] = (f32x4){0.f, 0.f, 0.f, 0.f};

    const int l15 = lane & 15, l16 = lane >> 4;

    for (int kc = 0; kc < H_SZ; kc += 32) {
        const float* ap = hs + (size_t)(r0 + s_row) * H_SZ + kc + s_kh * 16;
        float4 a0 = ((const float4*)ap)[0];
        float4 a1 = ((const float4*)ap)[1];
        float4 a2 = ((const float4*)ap)[2];
        float4 a3 = ((const float4*)ap)[3];
        unsigned pk[8];
        pk[0] = __builtin_amdgcn_perm(__float_as_uint(a0.y), __float_as_uint(a0.x), 0x07060302u);
        pk[1] = __builtin_amdgcn_perm(__float_as_uint(a0.w), __float_as_uint(a0.z), 0x07060302u);
        pk[2] = __builtin_amdgcn_perm(__float_as_uint(a1.y), __float_as_uint(a1.x), 0x07060302u);
        pk[3] = __builtin_amdgcn_perm(__float_as_uint(a1.w), __float_as_uint(a1.z), 0x07060302u);
        pk[4] = __builtin_amdgcn_perm(__float_as_uint(a2.y), __float_as_uint(a2.x), 0x07060302u);
        pk[5] = __builtin_amdgcn_perm(__float_as_uint(a2.w), __float_as_uint(a2.z), 0x07060302u);
        pk[6] = __builtin_amdgcn_perm(__float_as_uint(a3.y), __float_as_uint(a3.x), 0x07060302u);
        pk[7] = __builtin_amdgcn_perm(__float_as_uint(a3.w), __float_as_uint(a3.z), 0x07060302u);
        bf16x8 bld0 = *(const bf16x8*)(WdT + (size_t)(c0 + b_n) * H_SZ + kc + b_q * 8);
        bf16x8 bld1 = *(const bf16x8*)(WdT + (size_t)(c0 + b_n + 64) * H_SZ + kc + b_q * 8);
        __syncthreads();
        ((uint4*)&As[s_row * 40 + s_kh * 16])[0] = make_uint4(pk[0], pk[1], pk[2], pk[3]);
        ((uint4*)&As[s_row * 40 + s_kh * 16 + 8])[0] = make_uint4(pk[4], pk[5], pk[6], pk[7]);
        *(bf16x8*)(&Bs[b_n * 32 + b_q * 8]) = bld0;
        *(bf16x8*)(&Bs[(b_n + 64) * 32 + b_q * 8]) = bld1;
        __syncthreads();

        bf16x8 af[4], bf[4];
#pragma unroll
        for (int mi = 0; mi < 4; ++mi)
            af[mi] = *(const bf16x8*)(&As[(rw + mi * 16 + l15) * 40 + l16 * 8]);
#pragma unroll
        for (int ni = 0; ni < 4; ++ni)
            bf[ni] = *(const bf16x8*)(&Bs[(cw + ni * 16 + l15) * 32 + l16 * 8]);
#pragma unroll
        for (int mi = 0; mi < 4; ++mi)
#pragma unroll
            for (int ni = 0; ni < 4; ++ni)
                acc[mi][ni] = __builtin_amdgcn_mfma_f32_16x16x32_bf16(
                    af[mi], bf[ni], acc[mi][ni], 0, 0, 0);
    }

#pragma unroll
    for (int ni = 0; ni < 4; ++ni) {
        const int col = c0 + cw + ni * 16 + l15;
        const float bv = bias[col];
#pragma unroll
        for (int mi = 0; mi < 4; ++mi) {
            const int rowb = r0 + rw + mi * 16 + l16 * 4;
#pragma unroll
            for (int r = 0; r < 4; ++r)
                out[(size_t)(rowb + r) * V_SZ + col] = acc[mi][ni][r] + bv;
        }
    }
}

// final state copy
__global__ __launch_bounds__(256)
void copy_f4(const float* __restrict__ src, float* __restrict__ dst)
{
    int i = blockIdx.x * 256 + threadIdx.x;
    ((float4*)dst)[i] = ((const float4*)src)[i];
}

extern "C" void kernel_launch(void* const* d_in, const int* in_sizes, int n_in,
                              void* d_out, int out_size, void* d_ws, size_t ws_size,
                              hipStream_t stream)
{
    const float* inputs  = (const float*)d_in[0];
    const float* W_xh    = (const float*)d_in[1];
    const float* W_hh    = (const float*)d_in[2];
    const float* b_h     = (const float*)d_in[3];
    const float* W_dense = (const float*)d_in[4];
    const float* b_dense = (const float*)d_in[5];
    float* out = (float*)d_out;

    float* buf = (float*)d_ws;                          // xh -> hs in place
    float* P   = out;                                   // 4 MB K-split partials
    int*   FL  = (int*)(out + 1310720);                 // barrier flags @ +5.2 MB
    unsigned short* WdT = (unsigned short*)(out + (size_t)M1 * V_SZ); // 1 MB tail

    cvt_wdense<<<dim3(H_SZ / 64, V_SZ / 64), 256, 0, stream>>>(W_dense, WdT);

    gemm_f32_xh<<<dim3(H_SZ / 128, M1 / 128), 256, 0, stream>>>(
        inputs, W_xh, b_h, buf);

    tanh_inplace<<<dim3(BH / 1024), 256, 0, stream>>>(buf);

    init_bars<<<dim3(17), 256, 0, stream>>>(FL);        // zero 4352 >= 132*32 ints
    {
        void* args[4];
        args[0] = (void*)&buf;
        args[1] = (void*)&W_hh;
        args[2] = (void*)&P;
        args[3] = (void*)&FL;
        hipError_t e = hipLaunchCooperativeKernel((void*)scan_persistent,
                                                  dim3(256), dim3(SC_THREADS),
                                                  args, 0, stream);
        if (e != hipSuccess) {
            scan_persistent<<<dim3(256), dim3(SC_THREADS), 0, stream>>>(
                buf, W_hh, P, FL);
        }
    }

    gemm_out_mfma<<<dim3(V_SZ / 128, M1 / 128), 256, 0, stream>>>(
        buf, WdT, b_dense, out);

    copy_f4<<<dim3(BH / 1024), 256, 0, stream>>>(
        buf + (size_t)(T_STEPS - 1) * BH, out + (size_t)M1 * V_SZ);
}